// Round 4
// baseline (567.375 us; speedup 1.0000x reference)
//
#include <hip/hip_runtime.h>

#define NN 50000
#define NE 800000
#define DD 128
#define NB 782          // buckets of 64 nodes
#define BSTRIDE 784
#define RPS 50016       // rowptr per-conv stride
#define CHUNK 4096
#define BIN_BLOCKS ((NE + CHUNK - 1) / CHUNK)   // 196
#define H8SCALE 64.f
#define H8INV (1.f / 64.f)
#define HROWS (NN + 1)  // rows per quarter-plane; row NN is the all-zero row
#define NHALF 25000
#define OCTH 3125       // octets (8 nodes) per half-job
#define OCTSLOT 9375    // octets per slot (3 half-jobs)
#define GCHUNK 4        // octets per cursor grab
#define GBLOCKS 4096
#define XCCID_IMM 6164  // s_getreg: HW_REG_XCC_ID (id=20, offset=0, size=4)

typedef float floatx4 __attribute__((ext_vector_type(4)));
typedef float floatx2 __attribute__((ext_vector_type(2)));
typedef __bf16 bf16x8 __attribute__((ext_vector_type(8)));

__device__ __forceinline__ int clampn(int v) {
    return v < 0 ? 0 : (v >= NN ? NN - 1 : v);
}
__device__ __forceinline__ unsigned int f2bf(float f) {
    union { float f; unsigned int i; } v; v.f = f;
    unsigned int lsb = (v.i >> 16) & 1u;
    v.i += 0x7fffu + lsb;
    return (v.i >> 16) & 0xFFFFu;
}

// ---- W^T bf16 precompute + zero bHist/g/cursors (folds the memsets) ----
__global__ __launch_bounds__(256) void k_wt3(const float* __restrict__ w0,
                                             const float* __restrict__ w1,
                                             const float* __restrict__ w2,
                                             unsigned short* __restrict__ wtg,
                                             int* __restrict__ bHist,
                                             float* __restrict__ g,
                                             int* __restrict__ cursors) {
    int conv = blockIdx.x;
    const float* W = conv == 0 ? w0 : conv == 1 ? w1 : w2;
    unsigned short* o = wtg + conv * DD * DD;
    for (int i = threadIdx.x; i < BSTRIDE; i += 256) bHist[conv * BSTRIDE + i] = 0;
    for (int i = threadIdx.x; i < DD; i += 256) g[conv * DD + i] = 0.f;
    if (conv == 0) cursors[threadIdx.x] = 0;   // 256 ints (8 slots x 32 pad)
    for (int idx = threadIdx.x; idx < DD * DD; idx += 256) {
        int k = idx >> 7, c = idx & 127;
        o[c * DD + k] = (unsigned short)f2bf(W[idx]);
    }
}

// ---- pass 1: per-bucket edge counts ----
__global__ __launch_bounds__(256) void k_bcnt3(const int* __restrict__ e0,
                                               const int* __restrict__ e1,
                                               const int* __restrict__ e2,
                                               int* __restrict__ bHist) {
    __shared__ int hist[NB];
    const int* ei = (blockIdx.y == 0 ? e0 : blockIdx.y == 1 ? e1 : e2);
    int t = threadIdx.x;
    for (int b = t; b < NB; b += 256) hist[b] = 0;
    __syncthreads();
    int base = blockIdx.x * CHUNK;
    int chunk = NE - base; if (chunk > CHUNK) chunk = CHUNK;
    for (int i = t; i < chunk; i += 256) {
        int d = clampn(ei[NE + base + i]);
        atomicAdd(&hist[d >> 6], 1);
    }
    __syncthreads();
    for (int b = t; b < NB; b += 256)
        if (hist[b]) atomicAdd(&bHist[blockIdx.y * BSTRIDE + b], hist[b]);
}

// ---- pass 2: scan bucket counts -> bOff, bCur ----
__global__ __launch_bounds__(64) void k_bscan3(const int* __restrict__ bHist,
                                               int* __restrict__ bOff,
                                               int* __restrict__ bCur) {
    int conv = blockIdx.x;
    int lane = threadIdx.x;
    const int PER = (NB + 63) / 64;   // 13
    int basei = lane * PER;
    int loc[PER];
    int s = 0;
    for (int j = 0; j < PER; ++j) {
        int b = basei + j;
        int h = (b < NB) ? bHist[conv * BSTRIDE + b] : 0;
        loc[j] = h; s += h;
    }
    int incl = s;
    for (int off = 1; off < 64; off <<= 1) {
        int u = __shfl_up(incl, off);
        if (lane >= off) incl += u;
    }
    int run = incl - s;
    for (int j = 0; j < PER; ++j) {
        int b = basei + j;
        if (b < NB) {
            bOff[conv * BSTRIDE + b] = run;
            bCur[conv * BSTRIDE + b] = run;
            run += loc[j];
        }
    }
    if (lane == 63) bOff[conv * BSTRIDE + NB] = incl;
}

// ---- pass 3: block-local counting sort by bucket, coalesced flush ----
__global__ __launch_bounds__(256) void k_bin3(const int* __restrict__ e0,
                                              const int* __restrict__ e1,
                                              const int* __restrict__ e2,
                                              int* __restrict__ bCur,
                                              unsigned int* __restrict__ binned) {
    __shared__ int hist[NB];
    __shared__ int off[NB];
    __shared__ int delta[NB];
    __shared__ unsigned int stage[CHUNK];
    __shared__ unsigned short sbuck[CHUNK];
    const int* ei = (blockIdx.y == 0 ? e0 : blockIdx.y == 1 ? e1 : e2);
    int conv = blockIdx.y;
    int t = threadIdx.x;
    int base = blockIdx.x * CHUNK;
    int chunk = NE - base; if (chunk > CHUNK) chunk = CHUNK;

    for (int b = t; b < NB; b += 256) hist[b] = 0;
    __syncthreads();
    for (int i = t; i < chunk; i += 256) {
        int d = clampn(ei[NE + base + i]);
        atomicAdd(&hist[d >> 6], 1);
    }
    __syncthreads();
    if (t < 64) {
        const int PER = (NB + 63) / 64;
        int basei = t * PER;
        int loc[(NB + 63) / 64];
        int s = 0;
        for (int j = 0; j < PER; ++j) {
            int b = basei + j;
            int h = (b < NB) ? hist[b] : 0;
            loc[j] = h; s += h;
        }
        int incl = s;
        for (int o = 1; o < 64; o <<= 1) {
            int u = __shfl_up(incl, o);
            if (t >= o) incl += u;
        }
        int run = incl - s;
        for (int j = 0; j < PER; ++j) {
            int b = basei + j;
            if (b < NB) { off[b] = run; run += loc[j]; }
        }
    }
    __syncthreads();
    for (int b = t; b < NB; b += 256) {
        if (hist[b]) {
            int gp = atomicAdd(&bCur[conv * BSTRIDE + b], hist[b]);
            delta[b] = gp - off[b];
        }
    }
    __syncthreads();
    for (int i = t; i < chunk; i += 256) {
        int s = clampn(ei[base + i]);
        int d = clampn(ei[NE + base + i]);
        int b = d >> 6;
        int slot = atomicAdd(&off[b], 1);
        stage[slot] = (unsigned int)s | ((unsigned int)(d & 63) << 16);
        sbuck[slot] = (unsigned short)b;
    }
    __syncthreads();
    for (int i = t; i < chunk; i += 256)
        binned[(long)conv * NE + delta[sbuck[i]] + i] = stage[i];
}

// ---- pass 4: within-bucket sort by node -> adj, deg, rowptr ----
__global__ __launch_bounds__(256) void k_sort3(const unsigned int* __restrict__ binned,
                                               const int* __restrict__ bOff,
                                               int* __restrict__ adj,
                                               int* __restrict__ deg,
                                               int* __restrict__ rowptr) {
    __shared__ int cnt[64];
    __shared__ int cur[64];
    int b = blockIdx.x, conv = blockIdx.y;
    int t = threadIdx.x;
    int beg = bOff[conv * BSTRIDE + b], end = bOff[conv * BSTRIDE + b + 1];
    const unsigned int* bp = binned + (long)conv * NE;
    if (t < 64) cnt[t] = 0;
    __syncthreads();
    for (int i = beg + t; i < end; i += 256)
        atomicAdd(&cnt[(bp[i] >> 16) & 63], 1);
    __syncthreads();
    if (t < 64) {
        int c = cnt[t];
        int incl = c;
        for (int o = 1; o < 64; o <<= 1) {
            int u = __shfl_up(incl, o);
            if (t >= o) incl += u;
        }
        cur[t] = beg + incl - c;
        int v = b * 64 + t;
        if (v < NN) {
            deg[conv * NN + v] = c;
            rowptr[conv * RPS + v] = beg + incl - c;
            if (v == NN - 1) rowptr[conv * RPS + NN] = beg + incl;
        }
    }
    __syncthreads();
    for (int i = beg + t; i < end; i += 256) {
        unsigned int e = bp[i];
        int dl = (e >> 16) & 63;
        int pos = atomicAdd(&cur[dl], 1);
        adj[(long)conv * NE + pos] = (int)(e & 0xFFFFu);
    }
}

// ---- batched MFMA gemm: h' = bf16(x)@bf16(W) * rsqrt(deg+1) * 64 -> fp8,
// written as 4 quarter-planes of 32B rows per conv; zeroes each plane's row NN ----
__global__ __launch_bounds__(256) void k_gemmb(
    const float* __restrict__ x0, const float* __restrict__ x1, const float* __restrict__ x2,
    const unsigned short* __restrict__ wtg,
    const int* __restrict__ deg, unsigned char* __restrict__ hp8s, int n) {
    int conv = blockIdx.y;
    const float* x = conv == 0 ? x0 : conv == 1 ? x1 : x2;
    const int* dg = deg + conv * NN;
    unsigned char* hp = hp8s + (size_t)conv * 4 * HROWS * 32;

    __shared__ __align__(16) unsigned short wt[128 * 136];  // W^T bf16, padded
    __shared__ __align__(16) unsigned short xb[64 * 136];   // x rows bf16, padded
    int tid = threadIdx.x;
    int base = blockIdx.x * 64;

    if (blockIdx.x == 0 && tid < 32) {
        int q = tid >> 3, dw = tid & 7;
        *reinterpret_cast<unsigned int*>(hp + ((size_t)q * HROWS + NN) * 32 + dw * 4) = 0u;
    }

    const uint4* wg = reinterpret_cast<const uint4*>(wtg + conv * DD * DD);
#pragma unroll
    for (int it = 0; it < 8; ++it) {
        int chunk = it * 256 + tid;
        int c = chunk >> 4, gq = chunk & 15;
        *reinterpret_cast<uint4*>(&wt[c * 136 + gq * 8]) = wg[chunk];
    }
    const float4* x4p = reinterpret_cast<const float4*>(x);
#pragma unroll
    for (int it = 0; it < 8; ++it) {
        int idx = it * 256 + tid;
        int row = idx >> 5, c4 = idx & 31;
        int r = base + row;
        float4 v = (r < n) ? x4p[(long)r * 32 + c4] : float4{0.f, 0.f, 0.f, 0.f};
        unsigned int p0 = f2bf(v.x) | (f2bf(v.y) << 16);
        unsigned int p1 = f2bf(v.z) | (f2bf(v.w) << 16);
        uint2 pv = {p0, p1};
        *reinterpret_cast<uint2*>(&xb[row * 136 + c4 * 4]) = pv;
    }
    __syncthreads();

    int wave = tid >> 6, lane = tid & 63;
    int quad = lane >> 4, m = lane & 15;
    int rowb = wave * 16;

    bf16x8 a[4];
#pragma unroll
    for (int s = 0; s < 4; ++s)
        a[s] = *reinterpret_cast<const bf16x8*>(&xb[(rowb + m) * 136 + s * 32 + quad * 8]);

    floatx4 acc[8] = {};
#pragma unroll
    for (int j = 0; j < 8; ++j) {
#pragma unroll
        for (int s = 0; s < 4; ++s) {
            bf16x8 b = *reinterpret_cast<const bf16x8*>(&wt[(j * 16 + m) * 136 + s * 32 + quad * 8]);
            acc[j] = __builtin_amdgcn_mfma_f32_16x16x32_bf16(a[s], b, acc[j], 0, 0, 0);
        }
    }
#pragma unroll
    for (int r = 0; r < 4; ++r) {
        int rr = base + rowb + quad * 4 + r;
        if (rr < n) {
            float dvs = rsqrtf((float)(dg[rr] + 1)) * H8SCALE;
#pragma unroll
            for (int j = 0; j < 8; ++j) {
                float vv = acc[j][r] * dvs;
                int p = __builtin_amdgcn_cvt_pk_fp8_f32(vv, vv, 0, false);
                hp[((size_t)(j >> 1) * HROWS + rr) * 32 + ((j & 1) << 4) + m] =
                    (unsigned char)(p & 0xFF);
            }
        }
    }
}

// ---- gather over quarter-planes, XCD-partitioned ----
// 12 jobs = (conv, 32-ch plane), 1.6MB each. Slot k (real XCD id via s_getreg)
// owns half-jobs {3k,3k+1,3k+2} -> <=2 planes = 3.2MB, L2-resident with 17x reuse.
// Work via per-slot cursors (peek-then-RMW) + 8-slot steal loop => coverage is
// placement-independent. 8 lanes x dword = one 32B row, 8 nodes per wave.
#define FLUSHP do { if (curj >= 0) {                                                   \
        p0 += __shfl_xor(p0, 8); p0 += __shfl_xor(p0, 16); p0 += __shfl_xor(p0, 32);   \
        p1 += __shfl_xor(p1, 8); p1 += __shfl_xor(p1, 16); p1 += __shfl_xor(p1, 32);   \
        p2 += __shfl_xor(p2, 8); p2 += __shfl_xor(p2, 16); p2 += __shfl_xor(p2, 32);   \
        p3 += __shfl_xor(p3, 8); p3 += __shfl_xor(p3, 16); p3 += __shfl_xor(p3, 32);   \
        if (lane < 8) {                                                                \
            atomicAdd(&lacc[curj][(lane << 2) + 0], p0);                               \
            atomicAdd(&lacc[curj][(lane << 2) + 1], p1);                               \
            atomicAdd(&lacc[curj][(lane << 2) + 2], p2);                               \
            atomicAdd(&lacc[curj][(lane << 2) + 3], p3);                               \
        }                                                                              \
        p0 = p1 = p2 = p3 = 0.f; } } while (0)

__global__ __launch_bounds__(256) void k_gplane(const unsigned char* __restrict__ hp8,
                                                const int* __restrict__ rowptr,
                                                const int* __restrict__ adj,
                                                const float* __restrict__ cb0,
                                                const float* __restrict__ cb1,
                                                const float* __restrict__ cb2,
                                                float* __restrict__ gout,
                                                int* __restrict__ cursors) {
    __shared__ float lacc[12][32];
    int tid = threadIdx.x;
    for (int i = tid; i < 384; i += 256) lacc[i >> 5][i & 31] = 0.f;
    __syncthreads();

    int lane = tid & 63;
    int g8 = lane >> 3, l3 = lane & 7;
    int bpb = (lane & 56) << 2;            // bpermute byte base of own group
    unsigned ch4 = (unsigned)(l3 << 2);    // dword offset within 32B row

    int xcd = __builtin_amdgcn_s_getreg(XCCID_IMM) & 7;

    float p0 = 0.f, p1 = 0.f, p2 = 0.f, p3 = 0.f;
    int curj = -1;
    float4 b4 = {0.f, 0.f, 0.f, 0.f};
    const unsigned char* hpb = hp8;
    const int* rp = rowptr;
    const int* ad = adj;

    for (int st = 0; st < 8; ++st) {
        int s = (xcd + st) & 7;
        int* cp = cursors + s * 32;
        for (;;) {
            int c0 = OCTSLOT;
            if (lane == 0) {
                if (*(volatile int*)cp < OCTSLOT) c0 = atomicAdd(cp, GCHUNK);
            }
            c0 = __builtin_amdgcn_readfirstlane(c0);
            if (c0 >= OCTSLOT) break;
            int cend = c0 + GCHUNK; if (cend > OCTSLOT) cend = OCTSLOT;
            for (int o = c0; o < cend; ++o) {
                int hj = o / OCTH;
                int rem = o - hj * OCTH;
                int h = s * 3 + hj;
                int j = h >> 1;
                int nh = h & 1;
                if (j != curj) {
                    FLUSHP;
                    curj = j;
                    int conv = j >> 2, pl = j & 3;
                    hpb = hp8 + (size_t)j * (HROWS * 32);
                    rp = rowptr + conv * RPS;
                    ad = adj + (size_t)conv * NE;
                    const float* bias = conv == 0 ? cb0 : conv == 1 ? cb1 : cb2;
                    b4 = *reinterpret_cast<const float4*>(bias + pl * 32 + (l3 << 2));
                }
                int v = nh * NHALF + rem * 8 + g8;
                int beg = rp[v];
                int cnt = rp[v + 1] - beg;
                int cm = cnt, u;
                u = __shfl_xor(cm, 8);  cm = cm > u ? cm : u;
                u = __shfl_xor(cm, 16); cm = cm > u ? cm : u;
                u = __shfl_xor(cm, 32); cm = cm > u ? cm : u;

                float a0, a1, a2, a3;
                {
                    unsigned us = *reinterpret_cast<const unsigned*>(hpb + (((unsigned)v << 5) | ch4));
                    floatx2 f0 = __builtin_amdgcn_cvt_pk_f32_fp8((int)us, false);
                    floatx2 f1 = __builtin_amdgcn_cvt_pk_f32_fp8((int)us, true);
                    a0 = f0.x; a1 = f0.y; a2 = f1.x; a3 = f1.y;
                }
                for (int wk = 0; wk < cm; wk += 16) {
                    int w0 = wk + l3, w1 = w0 + 8;
                    int r = cm - wk;
                    int ai0 = beg + w0; ai0 = ai0 < NE ? ai0 : NE - 1;
                    int e0v = __builtin_nontemporal_load(ad + ai0);
                    int e1v = 0;
                    if (r > 8) {
                        int ai1 = beg + w1; ai1 = ai1 < NE ? ai1 : NE - 1;
                        e1v = __builtin_nontemporal_load(ad + ai1);
                    }
                    e0v = (w0 < cnt) ? e0v : NN;
                    e1v = (w1 < cnt) ? e1v : NN;
                    unsigned u0[8], u1[8];
#pragma unroll
                    for (int q = 0; q < 8; ++q) {
                        int sl2 = __builtin_amdgcn_ds_bpermute(bpb + 4 * q, e0v);
                        u0[q] = *reinterpret_cast<const unsigned*>(hpb + (((unsigned)sl2 << 5) | ch4));
                    }
                    if (r > 8) {
#pragma unroll
                        for (int q = 0; q < 8; ++q) {
                            int sl2 = __builtin_amdgcn_ds_bpermute(bpb + 4 * q, e1v);
                            u1[q] = *reinterpret_cast<const unsigned*>(hpb + (((unsigned)sl2 << 5) | ch4));
                        }
                    }
#pragma unroll
                    for (int q = 0; q < 8; ++q) {
                        floatx2 f0 = __builtin_amdgcn_cvt_pk_f32_fp8((int)u0[q], false);
                        floatx2 f1 = __builtin_amdgcn_cvt_pk_f32_fp8((int)u0[q], true);
                        a0 += f0.x; a1 += f0.y; a2 += f1.x; a3 += f1.y;
                    }
                    if (r > 8) {
#pragma unroll
                        for (int q = 0; q < 8; ++q) {
                            floatx2 f0 = __builtin_amdgcn_cvt_pk_f32_fp8((int)u1[q], false);
                            floatx2 f1 = __builtin_amdgcn_cvt_pk_f32_fp8((int)u1[q], true);
                            a0 += f0.x; a1 += f0.y; a2 += f1.x; a3 += f1.y;
                        }
                    }
                }
                float dv = rsqrtf((float)(cnt + 1)) * H8INV;
                p0 += fmaxf(dv * a0 + b4.x, 0.f);
                p1 += fmaxf(dv * a1 + b4.y, 0.f);
                p2 += fmaxf(dv * a2 + b4.z, 0.f);
                p3 += fmaxf(dv * a3 + b4.w, 0.f);
            }
        }
    }
    FLUSHP;
    __syncthreads();
    for (int i = tid; i < 384; i += 256) {
        float vv = lacc[i >> 5][i & 31];
        if (vv != 0.f) {
            int j = i >> 5, conv = j >> 2, pl = j & 3;
            unsafeAtomicAdd(&gout[conv * DD + pl * 32 + (i & 31)], vv);
        }
    }
}

// ---- head MLP: 256 threads, float4 weight reads, split-j reduction ----
__global__ __launch_bounds__(256) void k_head(const float* __restrict__ g,
    const float* __restrict__ w1, const float* __restrict__ b1,
    const float* __restrict__ w2, const float* __restrict__ b2,
    const float* __restrict__ w3, const float* __restrict__ b3,
    const float* __restrict__ f1w, const float* __restrict__ f1b,
    const float* __restrict__ f2w, const float* __restrict__ f2b,
    float* __restrict__ out) {
    __shared__ float xin[384], part[256], h1[128], h2[128], aw[3], xctx[128];
    int t = threadIdx.x;
    int o = t & 127, half = t >> 7;
    for (int i = t; i < 384; i += 256) xin[i] = g[i];
    __syncthreads();
    {
        const float4* wrow = reinterpret_cast<const float4*>(w1 + o * 384 + half * 192);
        const float* xi = xin + half * 192;
        float s = 0.f;
#pragma unroll
        for (int j4 = 0; j4 < 48; ++j4) {
            float4 w = wrow[j4];
            s += w.x * xi[j4 * 4] + w.y * xi[j4 * 4 + 1] + w.z * xi[j4 * 4 + 2] + w.w * xi[j4 * 4 + 3];
        }
        part[t] = s;
    }
    __syncthreads();
    if (t < 128) h1[t] = fmaxf(part[t] + part[t + 128] + b1[t], 0.f);
    __syncthreads();
    {
        const float4* wrow = reinterpret_cast<const float4*>(w2 + o * 128 + half * 64);
        const float* xi = h1 + half * 64;
        float s = 0.f;
#pragma unroll
        for (int j4 = 0; j4 < 16; ++j4) {
            float4 w = wrow[j4];
            s += w.x * xi[j4 * 4] + w.y * xi[j4 * 4 + 1] + w.z * xi[j4 * 4 + 2] + w.w * xi[j4 * 4 + 3];
        }
        part[t] = s;
    }
    __syncthreads();
    if (t < 128) h2[t] = fmaxf(part[t] + part[t + 128] + b2[t], 0.f);
    __syncthreads();
    if (t < 3) {
        float sl = b3[t];
        for (int j = 0; j < 128; ++j) sl += h2[j] * w3[t * 128 + j];
        aw[t] = sl;
    }
    __syncthreads();
    if (t == 0) {
        float mx = fmaxf(aw[0], fmaxf(aw[1], aw[2]));
        float e0 = expf(aw[0] - mx), e1 = expf(aw[1] - mx), e2 = expf(aw[2] - mx);
        float inv = 1.f / (e0 + e1 + e2);
        aw[0] = e0 * inv; aw[1] = e1 * inv; aw[2] = e2 * inv;
    }
    __syncthreads();
    if (t < 128) xctx[t] = aw[0] * xin[t] + aw[1] * xin[128 + t] + aw[2] * xin[256 + t];
    __syncthreads();
    {
        const float* fw = half ? f2w : f1w;
        const float* fb = half ? f2b : f1b;
        const float4* wrow = reinterpret_cast<const float4*>(fw + o * 128);
        float s = fb[o];
#pragma unroll
        for (int j4 = 0; j4 < 32; ++j4) {
            float4 w = wrow[j4];
            s += w.x * xctx[j4 * 4] + w.y * xctx[j4 * 4 + 1] + w.z * xctx[j4 * 4 + 2] + w.w * xctx[j4 * 4 + 3];
        }
        out[half * 128 + o] = tanhf(s);
    }
}

extern "C" void kernel_launch(void* const* d_in, const int* in_sizes, int n_in,
                              void* d_out, int out_size, void* d_ws, size_t ws_size,
                              hipStream_t stream) {
    (void)in_sizes; (void)n_in; (void)out_size; (void)ws_size;

    const float* x[3]  = {(const float*)d_in[0], (const float*)d_in[1], (const float*)d_in[2]};
    const int*   ei[3] = {(const int*)d_in[3], (const int*)d_in[4], (const int*)d_in[5]};
    const float* cw[3] = {(const float*)d_in[6], (const float*)d_in[8], (const float*)d_in[10]};
    const float* cb[3] = {(const float*)d_in[7], (const float*)d_in[9], (const float*)d_in[11]};

    // layout (binned overlaid by hp8: binned dead after k_sort3)
    char* ws = (char*)d_ws;
    int*            adj    = (int*)ws;                         //  9,600,000
    int*            deg    = (int*)(ws + 9600000);             //    600,000
    int*            rowptr = (int*)(ws + 10200000);            //    600,192
    int*            bHist  = (int*)(ws + 10800192);            //      9,408
    int*            bOff   = (int*)(ws + 10809600);            //      9,408
    int*            bCur   = (int*)(ws + 10819008);            //      9,408
    float*          g      = (float*)(ws + 10828416);          //      1,536
    unsigned short* wtg    = (unsigned short*)(ws + 10830080); //     98,304
    char*           uni    = ws + 10928384;                    // union region
    unsigned int*   binned = (unsigned int*)uni;               //  9,600,000
    unsigned char*  hp8    = (unsigned char*)uni;              // 19,200,384 (12 planes x HROWS x 32)
    int*            cursors= (int*)(ws + 30128768);            //      1,024 (8 slots x 128B)

    dim3 bin_grid(BIN_BLOCKS, 3);
    k_wt3   <<<3, 256, 0, stream>>>(cw[0], cw[1], cw[2], wtg, bHist, g, cursors);
    k_bcnt3 <<<bin_grid, 256, 0, stream>>>(ei[0], ei[1], ei[2], bHist);
    k_bscan3<<<3, 64, 0, stream>>>(bHist, bOff, bCur);
    k_bin3  <<<bin_grid, 256, 0, stream>>>(ei[0], ei[1], ei[2], bCur, binned);
    k_sort3 <<<dim3(NB, 3), 256, 0, stream>>>(binned, bOff, adj, deg, rowptr);

    k_gemmb<<<dim3(NB, 3), 256, 0, stream>>>(x[0], x[1], x[2], wtg, deg, hp8, NN);
    k_gplane<<<GBLOCKS, 256, 0, stream>>>(hp8, rowptr, adj, cb[0], cb[1], cb[2], g, cursors);

    k_head<<<1, 256, 0, stream>>>(g,
        (const float*)d_in[12], (const float*)d_in[13],
        (const float*)d_in[14], (const float*)d_in[15],
        (const float*)d_in[16], (const float*)d_in[17],
        (const float*)d_in[18], (const float*)d_in[19],
        (const float*)d_in[20], (const float*)d_in[21],
        (float*)d_out);
}